// Round 6
// baseline (342.050 us; speedup 1.0000x reference)
//
#include <hip/hip_runtime.h>
#include <math.h>

// ---------- problem constants ----------
constexpr int NN0 = 524288, NN1 = 65536, NN2 = 8192, NN3 = 1024;
constexpr int E0 = 655360, E1 = 81920, E2 = 10240;
constexpr int ETOT = E0 + E1 + E2;           // 747520
constexpr int NTOT = NN1 + NN2 + NN3;        // 74752

static inline int cdiv(int a, int b) { return (a + b - 1) / b; }

typedef __bf16 bf16x8_t __attribute__((ext_vector_type(8)));
typedef float f32x4_t __attribute__((ext_vector_type(4)));

__device__ __forceinline__ unsigned short f2bf(float f) {
    union { float f; unsigned int u; } v; v.f = f;
    unsigned int r = v.u + 0x7fffu + ((v.u >> 16) & 1u);
    return (unsigned short)(r >> 16);
}
__device__ __forceinline__ float bf2f(unsigned short h) {
    union { unsigned int u; float f; } v; v.u = ((unsigned int)h) << 16;
    return v.f;
}

// ---------- x fp32 -> bf16 (105 MB, becomes L3-resident) ----------
// 52,428,800 elems, 8 per thread: 25600 blocks x 256.
__global__ void convert_x(const float* __restrict__ x, unsigned short* __restrict__ xb) {
    size_t i = ((size_t)blockIdx.x * 256 + threadIdx.x) * 8;
    f32x4_t a = *reinterpret_cast<const f32x4_t*>(x + i);
    f32x4_t b = *reinterpret_cast<const f32x4_t*>(x + i + 4);
    union { ushort4 u4[2]; int4 i4; } o;
    o.u4[0].x = f2bf(a[0]); o.u4[0].y = f2bf(a[1]); o.u4[0].z = f2bf(a[2]); o.u4[0].w = f2bf(a[3]);
    o.u4[1].x = f2bf(b[0]); o.u4[1].y = f2bf(b[1]); o.u4[1].z = f2bf(b[2]); o.u4[1].w = f2bf(b[3]);
    *reinterpret_cast<int4*>(xb + i) = o.i4;
}

// ---------- fused CSR build ----------
__global__ void count_all(const int* __restrict__ dst0, const int* __restrict__ dst1,
                          const int* __restrict__ dst2, int* __restrict__ cnt) {
    int i = blockIdx.x * 256 + threadIdx.x;
    if (i < E0) atomicAdd(&cnt[dst0[i]], 1);
    else if (i < E0 + E1) atomicAdd(&cnt[NN1 + dst1[i - E0]], 1);
    else if (i < ETOT) atomicAdd(&cnt[NN1 + NN2 + dst2[i - E0 - E1]], 1);
}

__global__ __launch_bounds__(1024) void scan1(const int* __restrict__ cnt, int n,
                                              int* __restrict__ ofs, int* __restrict__ sums) {
    __shared__ int s[1024];
    int i = blockIdx.x * 1024 + threadIdx.x;
    int v = (i < n) ? cnt[i] : 0;
    s[threadIdx.x] = v;
    __syncthreads();
    for (int off = 1; off < 1024; off <<= 1) {
        int t = (threadIdx.x >= off) ? s[threadIdx.x - off] : 0;
        __syncthreads();
        s[threadIdx.x] += t;
        __syncthreads();
    }
    if (i < n) ofs[i] = s[threadIdx.x] - v;
    if (threadIdx.x == 1023) sums[blockIdx.x] = s[1023];
}

__global__ void scan3(const int* __restrict__ sums, int n,
                      int* __restrict__ ofs, int* __restrict__ cursor) {
    __shared__ int pref_s;
    int c = (blockIdx.x * 256) >> 10;
    if (threadIdx.x < 64) {
        int v = 0;
        for (int j = threadIdx.x; j < c; j += 64) v += sums[j];
        for (int o = 32; o; o >>= 1) v += __shfl_down(v, o);
        if (threadIdx.x == 0) pref_s = v;
    }
    __syncthreads();
    int i = blockIdx.x * 256 + threadIdx.x;
    if (i < n) {
        int v = ofs[i] + pref_s;
        ofs[i] = v;
        cursor[i] = v;
    }
    if (blockIdx.x == 0 && threadIdx.x == 0) ofs[n] = ETOT;
}

__global__ void scatter_all(const int* __restrict__ src0, const int* __restrict__ dst0,
                            const int* __restrict__ src1, const int* __restrict__ dst1,
                            const int* __restrict__ src2, const int* __restrict__ dst2,
                            int* __restrict__ cursor, int* __restrict__ perm) {
    int i = blockIdx.x * 256 + threadIdx.x;
    if (i < E0) {
        int p = atomicAdd(&cursor[dst0[i]], 1);
        perm[p] = src0[i];
    } else if (i < E0 + E1) {
        int j = i - E0;
        int p = atomicAdd(&cursor[NN1 + dst1[j]], 1);
        perm[p] = src1[j];
    } else if (i < ETOT) {
        int j = i - E0 - E1;
        int p = atomicAdd(&cursor[NN1 + NN2 + dst2[j]], 1);
        perm[p] = src2[j];
    }
}

// ---------- weight prep: four pre-transposed bf16 halves ----------
__global__ void prep_w(const float* __restrict__ Wl0, const float* __restrict__ Wr0,
                       unsigned short* __restrict__ Wt0a, unsigned short* __restrict__ Wt0b,
                       const float* __restrict__ Wl1, const float* __restrict__ Wr1,
                       unsigned short* __restrict__ Wt1a, unsigned short* __restrict__ Wt1b) {
    int b = blockIdx.x, t = threadIdx.x;
    if (b < 128) {
        int idx = b * 256 + t; int n = idx >> 7, k = idx & 127;
        Wt0a[idx] = f2bf(k < 100 ? Wl0[k * 256 + n] : 0.f);
    } else if (b < 256) {
        int idx = (b - 128) * 256 + t; int n = idx >> 7, k = idx & 127;
        Wt0b[idx] = f2bf(k < 100 ? Wr0[k * 256 + n] : 0.f);
    } else if (b < 512) {
        int idx = (b - 256) * 256 + t; int n = idx >> 8, k = idx & 255;
        Wt1a[idx] = f2bf(Wl1[k * 256 + n]);
    } else {
        int idx = (b - 512) * 256 + t; int n = idx >> 8, k = idx & 255;
        Wt1b[idx] = f2bf(Wr1[k * 256 + n]);
    }
}

// ---------- fused layer 0: gather-mean(xb bf16) + dual MFMA GEMM + ReLU -> h1 bf16 ----------
// Block: 128 dst rows x full N=256, 512 threads (8 waves, 2M x 4N of 64x64).
// As[128][136] bf16 (K=128: agg 0..99 | zeros 100..127), re-staged from xb for pass 1.
__global__ __launch_bounds__(512) void fused_l0(const unsigned short* __restrict__ xb,
                                                const int* __restrict__ perm,
                                                const int* __restrict__ ofs,
                                                const unsigned short* __restrict__ Wt0a,
                                                const unsigned short* __restrict__ Wt0b,
                                                const float* __restrict__ bias,
                                                unsigned short* __restrict__ h1) {
    __shared__ unsigned short As[128][136];
    __shared__ unsigned short Bs[256][40];
    int tid = threadIdx.x;
    int lane = tid & 63, wid = tid >> 6;
    int bm = blockIdx.x * 128;

    // ---- gather phase: wave wid aggregates rows [wid*16, wid*16+16) ----
    {
        int g = lane >> 5, l5 = lane & 31;
        bool act = l5 < 25;
        for (int r = 0; r < 16; ++r) {
            int row = wid * 16 + r;
            int node = bm + row;
            int s0 = ofs[node], s1 = ofs[node + 1];
            float inv = 1.0f / fmaxf((float)(s1 - s0), 1.0f);
            f32x4_t A0 = {0.f, 0.f, 0.f, 0.f}, A1 = A0, A2 = A0, A3 = A0;
            int e = s0;
            for (; e + 8 <= s1; e += 8) {
                int p0 = perm[e + 0 + g];
                int p1 = perm[e + 2 + g];
                int p2 = perm[e + 4 + g];
                int p3 = perm[e + 6 + g];
                if (act) {
                    ushort4 v0 = *reinterpret_cast<const ushort4*>(xb + (size_t)p0 * 100 + l5 * 4);
                    ushort4 v1 = *reinterpret_cast<const ushort4*>(xb + (size_t)p1 * 100 + l5 * 4);
                    ushort4 v2 = *reinterpret_cast<const ushort4*>(xb + (size_t)p2 * 100 + l5 * 4);
                    ushort4 v3 = *reinterpret_cast<const ushort4*>(xb + (size_t)p3 * 100 + l5 * 4);
                    A0[0] += bf2f(v0.x); A0[1] += bf2f(v0.y); A0[2] += bf2f(v0.z); A0[3] += bf2f(v0.w);
                    A1[0] += bf2f(v1.x); A1[1] += bf2f(v1.y); A1[2] += bf2f(v1.z); A1[3] += bf2f(v1.w);
                    A2[0] += bf2f(v2.x); A2[1] += bf2f(v2.y); A2[2] += bf2f(v2.z); A2[3] += bf2f(v2.w);
                    A3[0] += bf2f(v3.x); A3[1] += bf2f(v3.y); A3[2] += bf2f(v3.z); A3[3] += bf2f(v3.w);
                }
            }
            for (; e < s1; e += 2) {
                int idx = e + g;
                if (idx < s1 && act) {
                    ushort4 v = *reinterpret_cast<const ushort4*>(xb + (size_t)perm[idx] * 100 + l5 * 4);
                    A0[0] += bf2f(v.x); A0[1] += bf2f(v.y); A0[2] += bf2f(v.z); A0[3] += bf2f(v.w);
                }
            }
            f32x4_t a = (A0 + A1) + (A2 + A3);
#pragma unroll
            for (int c = 0; c < 4; c++) a[c] += __shfl_xor(a[c], 32);
            if (lane < 25) {
                ushort4 o;
                o.x = f2bf(a[0] * inv); o.y = f2bf(a[1] * inv);
                o.z = f2bf(a[2] * inv); o.w = f2bf(a[3] * inv);
                *reinterpret_cast<ushort4*>(&As[row][lane * 4]) = o;
            } else if (lane < 32) {
                *reinterpret_cast<ushort4*>(&As[row][100 + (lane - 25) * 4]) = make_ushort4(0, 0, 0, 0);
            }
        }
    }

    f32x4_t acc[4][4];
#pragma unroll
    for (int i = 0; i < 4; i++)
#pragma unroll
        for (int j = 0; j < 4; j++)
#pragma unroll
            for (int r = 0; r < 4; r++) acc[i][j][r] = 0.f;

    int r0 = lane & 15, kg = lane >> 4;
    int wm = (wid >> 2) * 64, wn = (wid & 3) * 64;

    for (int pass = 0; pass < 2; ++pass) {
        const unsigned short* W = pass ? Wt0b : Wt0a;
        if (pass) {
            __syncthreads();   // all pass-0 MFMA done reading As
            // re-stage As <- xb dst rows (bf16 copy), 4 threads/row
            int rown = tid >> 2, q = tid & 3;
            for (int c4 = q; c4 < 25; c4 += 4) {
                *reinterpret_cast<ushort4*>(&As[rown][c4 * 4]) =
                    *reinterpret_cast<const ushort4*>(xb + (size_t)(bm + rown) * 100 + c4 * 4);
            }
            if (q == 3) {
#pragma unroll
                for (int c4 = 25; c4 < 32; ++c4)
                    *reinterpret_cast<ushort4*>(&As[rown][c4 * 4]) = make_ushort4(0, 0, 0, 0);
            }
        }
        for (int ks = 0; ks < 4; ++ks) {
            __syncthreads();
            for (int c = tid; c < 1024; c += 512) {
                int n = c >> 2, k8 = (c & 3) << 3;
                *reinterpret_cast<int4*>(&Bs[n][k8]) =
                    *reinterpret_cast<const int4*>(&W[(size_t)n * 128 + ks * 32 + k8]);
            }
            __syncthreads();
            bf16x8_t af[4], bfv[4];
#pragma unroll
            for (int mi = 0; mi < 4; mi++)
                af[mi] = *reinterpret_cast<const bf16x8_t*>(&As[wm + mi * 16 + r0][ks * 32 + kg * 8]);
#pragma unroll
            for (int ni = 0; ni < 4; ni++)
                bfv[ni] = *reinterpret_cast<const bf16x8_t*>(&Bs[wn + ni * 16 + r0][kg * 8]);
#pragma unroll
            for (int mi = 0; mi < 4; mi++)
#pragma unroll
                for (int ni = 0; ni < 4; ni++)
                    acc[mi][ni] = __builtin_amdgcn_mfma_f32_16x16x32_bf16(af[mi], bfv[ni], acc[mi][ni], 0, 0, 0);
        }
    }

    int cc = lane & 15, rr = (lane >> 4) * 4;
#pragma unroll
    for (int mi = 0; mi < 4; mi++) {
#pragma unroll
        for (int ni = 0; ni < 4; ni++) {
            int col = wn + ni * 16 + cc;
            float b = bias[col];
#pragma unroll
            for (int j = 0; j < 4; j++) {
                int row = bm + wm + mi * 16 + rr + j;
                float v = fmaxf(acc[mi][ni][j] + b, 0.f);
                h1[(size_t)row * 256 + col] = f2bf(v);
            }
        }
    }
}

// ---------- fused layer 1: gather-mean(h1) + dual MFMA GEMM + ReLU -> h2 fp32 ----------
__global__ __launch_bounds__(512) void fused_l1(const unsigned short* __restrict__ h1,
                                                const int* __restrict__ perm,
                                                const int* __restrict__ ofs,
                                                const unsigned short* __restrict__ Wt1a,
                                                const unsigned short* __restrict__ Wt1b,
                                                const float* __restrict__ bias,
                                                float* __restrict__ h2) {
    __shared__ unsigned short As[64][264];
    __shared__ unsigned short Bs[128][40];
    int tid = threadIdx.x;
    int lane = tid & 63, wid = tid >> 6;
    int bm = blockIdx.y * 64, bn = blockIdx.x * 128;

    for (int r = 0; r < 8; ++r) {
        int row = wid * 8 + r;
        int node = bm + row;
        int s0 = ofs[node], s1 = ofs[node + 1];
        float inv = 1.0f / fmaxf((float)(s1 - s0), 1.0f);
        float ac[4][4] = {};
        int e = s0;
        for (; e + 4 <= s1; e += 4) {
            ushort4 v[4];
#pragma unroll
            for (int u = 0; u < 4; u++)
                v[u] = *reinterpret_cast<const ushort4*>(h1 + (size_t)perm[e + u] * 256 + lane * 4);
#pragma unroll
            for (int u = 0; u < 4; u++) {
                ac[u][0] += bf2f(v[u].x); ac[u][1] += bf2f(v[u].y);
                ac[u][2] += bf2f(v[u].z); ac[u][3] += bf2f(v[u].w);
            }
        }
        for (; e < s1; e++) {
            ushort4 v = *reinterpret_cast<const ushort4*>(h1 + (size_t)perm[e] * 256 + lane * 4);
            ac[0][0] += bf2f(v.x); ac[0][1] += bf2f(v.y);
            ac[0][2] += bf2f(v.z); ac[0][3] += bf2f(v.w);
        }
        ushort4 o;
        o.x = f2bf((ac[0][0] + ac[1][0] + ac[2][0] + ac[3][0]) * inv);
        o.y = f2bf((ac[0][1] + ac[1][1] + ac[2][1] + ac[3][1]) * inv);
        o.z = f2bf((ac[0][2] + ac[1][2] + ac[2][2] + ac[3][2]) * inv);
        o.w = f2bf((ac[0][3] + ac[1][3] + ac[2][3] + ac[3][3]) * inv);
        *reinterpret_cast<ushort4*>(&As[row][lane * 4]) = o;
    }

    f32x4_t acc[2][2];
#pragma unroll
    for (int i = 0; i < 2; i++)
#pragma unroll
        for (int j = 0; j < 2; j++)
#pragma unroll
            for (int r = 0; r < 4; r++) acc[i][j][r] = 0.f;

    int r0 = lane & 15, kg = lane >> 4;
    int wm = (wid >> 2) * 32, wn = (wid & 3) * 32;

    for (int pass = 0; pass < 2; ++pass) {
        const unsigned short* W = pass ? Wt1b : Wt1a;
        if (pass) {
            __syncthreads();
            for (int c = tid; c < 2048; c += 512) {
                int row = c >> 5, k8 = (c & 31) << 3;
                *reinterpret_cast<int4*>(&As[row][k8]) =
                    *reinterpret_cast<const int4*>(&h1[(size_t)(bm + row) * 256 + k8]);
            }
        }
        for (int ks = 0; ks < 8; ++ks) {
            __syncthreads();
            {
                int c = tid;
                int n = c >> 2, k8 = (c & 3) << 3;
                *reinterpret_cast<int4*>(&Bs[n][k8]) =
                    *reinterpret_cast<const int4*>(&W[(size_t)(bn + n) * 256 + ks * 32 + k8]);
            }
            __syncthreads();
            bf16x8_t af[2], bfv[2];
#pragma unroll
            for (int mi = 0; mi < 2; mi++)
                af[mi] = *reinterpret_cast<const bf16x8_t*>(&As[wm + mi * 16 + r0][ks * 32 + kg * 8]);
#pragma unroll
            for (int ni = 0; ni < 2; ni++)
                bfv[ni] = *reinterpret_cast<const bf16x8_t*>(&Bs[wn + ni * 16 + r0][kg * 8]);
#pragma unroll
            for (int mi = 0; mi < 2; mi++)
#pragma unroll
                for (int ni = 0; ni < 2; ni++)
                    acc[mi][ni] = __builtin_amdgcn_mfma_f32_16x16x32_bf16(af[mi], bfv[ni], acc[mi][ni], 0, 0, 0);
        }
    }

    int cc = lane & 15, rr = (lane >> 4) * 4;
#pragma unroll
    for (int mi = 0; mi < 2; mi++) {
#pragma unroll
        for (int ni = 0; ni < 2; ni++) {
            int col = bn + wn + ni * 16 + cc;
            float b = bias[col];
#pragma unroll
            for (int j = 0; j < 4; j++) {
                int row = bm + wm + mi * 16 + rr + j;
                h2[(size_t)row * 256 + col] = fmaxf(acc[mi][ni][j] + b, 0.f);
            }
        }
    }
}

// ---------- layer-2 aggregate: h2 fp32 (D=256) ----------
__global__ void agg_vec4_256(const float* __restrict__ x, const int* __restrict__ perm,
                             const int* __restrict__ ofs, float* __restrict__ agg, int nrows) {
    int wave = (blockIdx.x * blockDim.x + threadIdx.x) >> 6;
    int lane = threadIdx.x & 63;
    if (wave >= nrows) return;
    int s0 = ofs[wave], s1 = ofs[wave + 1];
    float4 acc = make_float4(0.f, 0.f, 0.f, 0.f);
    for (int e = s0; e < s1; e++) {
        const float4* xr = (const float4*)(x + (size_t)perm[e] * 256);
        float4 v = xr[lane];
        acc.x += v.x; acc.y += v.y; acc.z += v.z; acc.w += v.w;
    }
    float inv = 1.0f / fmaxf((float)(s1 - s0), 1.0f);
    acc.x *= inv; acc.y *= inv; acc.z *= inv; acc.w *= inv;
    ((float4*)(agg + (size_t)wave * 256))[lane] = acc;
}

// ---------- layer-2: fp32 dual GEMM with fused log_softmax ----------
__global__ __launch_bounds__(256) void gemm2_fused(const float* __restrict__ A1, const float* __restrict__ W1, int K1,
                                                   const float* __restrict__ A2, const float* __restrict__ W2, int K2,
                                                   const float* __restrict__ bias, float* __restrict__ out,
                                                   int M, int N) {
    __shared__ float As[16][65];
    __shared__ float Bs[16][64];
    int tid = threadIdx.x;
    int tx = tid & 15, ty = tid >> 4;
    int bm = blockIdx.y * 64;
    float acc[4][4] = {};
    for (int pass = 0; pass < 2; ++pass) {
        const float* A = pass ? A2 : A1;
        const float* W = pass ? W2 : W1;
        int K = pass ? K2 : K1;
        for (int k0 = 0; k0 < K; k0 += 16) {
#pragma unroll
            for (int i = 0; i < 4; i++) {
                int L = i * 256 + tid;
                int m = L >> 4, k = L & 15;
                int gm = bm + m, gk = k0 + k;
                float v = 0.f;
                if (gm < M && gk < K) v = A[(size_t)gm * K + gk];
                As[k][m] = v;
            }
#pragma unroll
            for (int i = 0; i < 4; i++) {
                int L = i * 256 + tid;
                int n = L & 63, k = L >> 6;
                int gk = k0 + k;
                float v = 0.f;
                if (gk < K && n < N) v = W[(size_t)gk * N + n];
                Bs[k][n] = v;
            }
            __syncthreads();
#pragma unroll
            for (int k = 0; k < 16; k++) {
                float a[4], b[4];
#pragma unroll
                for (int i = 0; i < 4; i++) a[i] = As[k][ty * 4 + i];
#pragma unroll
                for (int j = 0; j < 4; j++) b[j] = Bs[k][tx * 4 + j];
#pragma unroll
                for (int i = 0; i < 4; i++)
#pragma unroll
                    for (int j = 0; j < 4; j++) acc[i][j] += a[i] * b[j];
            }
            __syncthreads();
        }
    }
#pragma unroll
    for (int i = 0; i < 4; i++) {
        int gm = bm + ty * 4 + i;
        float vals[4];
        float vmax = -1e30f;
#pragma unroll
        for (int j = 0; j < 4; j++) {
            int gn = tx * 4 + j;
            vals[j] = (gn < N) ? acc[i][j] + bias[gn] : -1e30f;
            vmax = fmaxf(vmax, vals[j]);
        }
#pragma unroll
        for (int o = 1; o < 16; o <<= 1) vmax = fmaxf(vmax, __shfl_xor(vmax, o));
        float se = 0.f;
#pragma unroll
        for (int j = 0; j < 4; j++) {
            int gn = tx * 4 + j;
            if (gn < N) se += expf(vals[j] - vmax);
        }
#pragma unroll
        for (int o = 1; o < 16; o <<= 1) se += __shfl_xor(se, o);
        float ls = logf(se);
#pragma unroll
        for (int j = 0; j < 4; j++) {
            int gn = tx * 4 + j;
            if (gn < N && gm < M) out[(size_t)gm * N + gn] = vals[j] - vmax - ls;
        }
    }
}

extern "C" void kernel_launch(void* const* d_in, const int* in_sizes, int n_in,
                              void* d_out, int out_size, void* d_ws, size_t ws_size,
                              hipStream_t stream) {
    const float* x   = (const float*)d_in[0];
    const int* src0  = (const int*)d_in[1];
    const int* dst0  = (const int*)d_in[2];
    const int* src1  = (const int*)d_in[3];
    const int* dst1  = (const int*)d_in[4];
    const int* src2  = (const int*)d_in[5];
    const int* dst2  = (const int*)d_in[6];
    const float* Wl0 = (const float*)d_in[7];
    const float* bl0 = (const float*)d_in[8];
    const float* Wr0 = (const float*)d_in[9];
    const float* Wl1 = (const float*)d_in[10];
    const float* bl1 = (const float*)d_in[11];
    const float* Wr1 = (const float*)d_in[12];
    const float* Wl2 = (const float*)d_in[13];
    const float* bl2 = (const float*)d_in[14];
    const float* Wr2 = (const float*)d_in[15];
    float* out = (float*)d_out;

    // ---- workspace layout ----
    char* p = (char*)d_ws;
    auto alloc = [&](size_t bytes) { char* r = p; p += (bytes + 255) & ~(size_t)255; return r; };
    unsigned short* xb   = (unsigned short*)alloc((size_t)NN0 * 100 * 2 + 16);  // bf16 x, L3-resident
    unsigned short* h1   = (unsigned short*)alloc((size_t)NN1 * 256 * 2);
    float* h2    = (float*)alloc((size_t)NN2 * 256 * 4);
    float* agg2  = (float*)alloc((size_t)NN3 * 256 * 4);
    unsigned short* Wt0a = (unsigned short*)alloc(256 * 128 * 2);
    unsigned short* Wt0b = (unsigned short*)alloc(256 * 128 * 2);
    unsigned short* Wt1a = (unsigned short*)alloc(256 * 256 * 2);
    unsigned short* Wt1b = (unsigned short*)alloc(256 * 256 * 2);
    int* cnt    = (int*)alloc((size_t)NTOT * 4);
    int* ofs    = (int*)alloc((size_t)(NTOT + 1) * 4);
    int* cursor = (int*)alloc((size_t)(NTOT + 1) * 4);
    int* sums   = (int*)alloc(128 * 4);
    int* perm   = (int*)alloc((size_t)ETOT * 4);

    // ---- convert + weight prep + fused CSR build ----
    convert_x<<<(NN0 * 100) / (256 * 8), 256, 0, stream>>>(x, xb);
    prep_w<<<768, 256, 0, stream>>>(Wl0, Wr0, Wt0a, Wt0b, Wl1, Wr1, Wt1a, Wt1b);
    hipMemsetAsync(cnt, 0, (size_t)NTOT * 4, stream);
    count_all<<<cdiv(ETOT, 256), 256, 0, stream>>>(dst0, dst1, dst2, cnt);
    int nb = cdiv(NTOT, 1024);   // 73
    scan1<<<nb, 1024, 0, stream>>>(cnt, NTOT, ofs, sums);
    scan3<<<cdiv(NTOT, 256), 256, 0, stream>>>(sums, NTOT, ofs, cursor);
    scatter_all<<<cdiv(ETOT, 256), 256, 0, stream>>>(src0, dst0, src1, dst1, src2, dst2, cursor, perm);

    // ---- layer 0 (fused gather + dual GEMM + ReLU) ----
    fused_l0<<<NN1 / 128, 512, 0, stream>>>(xb, perm, ofs, Wt0a, Wt0b, bl0, h1);

    // ---- layer 1 (fused gather + dual GEMM + ReLU) ----
    {
        dim3 grid(2, NN2 / 64);
        fused_l1<<<grid, 512, 0, stream>>>(h1, perm, ofs + NN1, Wt1a, Wt1b, bl1, h2);
    }

    // ---- layer 2 (fp32, fused log_softmax) ----
    agg_vec4_256<<<cdiv(NN3 * 64, 256), 256, 0, stream>>>(h2, perm, ofs + NN1 + NN2, agg2, NN3);
    {
        dim3 grid(1, cdiv(NN3, 64));
        gemm2_fused<<<grid, 256, 0, stream>>>(agg2, Wl2, 256, h2, Wr2, 256, bl2, out, NN3, 47);
    }
}

// Round 7
// 272.944 us; speedup vs baseline: 1.2532x; 1.2532x over previous
//
#include <hip/hip_runtime.h>
#include <math.h>

// ---------- problem constants ----------
constexpr int NN1 = 65536, NN2 = 8192, NN3 = 1024;
constexpr int E0 = 655360, E1 = 81920, E2 = 10240;
constexpr int ETOT = E0 + E1 + E2;           // 747520
constexpr int NTOT = NN1 + NN2 + NN3;        // 74752

static inline int cdiv(int a, int b) { return (a + b - 1) / b; }

typedef __bf16 bf16x8_t __attribute__((ext_vector_type(8)));
typedef float f32x4_t __attribute__((ext_vector_type(4)));

__device__ __forceinline__ unsigned short f2bf(float f) {
    union { float f; unsigned int u; } v; v.f = f;
    unsigned int r = v.u + 0x7fffu + ((v.u >> 16) & 1u);
    return (unsigned short)(r >> 16);
}
__device__ __forceinline__ float bf2f(unsigned short h) {
    union { unsigned int u; float f; } v; v.u = ((unsigned int)h) << 16;
    return v.f;
}

// ---------- fused CSR count + weight prep (merged dispatch) ----------
// blocks [0, CB): count atomics; blocks [CB, CB+768): prep_w.
constexpr int CB = (ETOT + 255) / 256;   // 2920
__global__ void count_prep(const int* __restrict__ dst0, const int* __restrict__ dst1,
                           const int* __restrict__ dst2, int* __restrict__ cnt,
                           const float* __restrict__ Wl0, const float* __restrict__ Wr0,
                           unsigned short* __restrict__ Wt0a, unsigned short* __restrict__ Wt0b,
                           const float* __restrict__ Wl1, const float* __restrict__ Wr1,
                           unsigned short* __restrict__ Wt1a, unsigned short* __restrict__ Wt1b) {
    int b = blockIdx.x, t = threadIdx.x;
    if (b < CB) {
        int i = b * 256 + t;
        if (i < E0) atomicAdd(&cnt[dst0[i]], 1);
        else if (i < E0 + E1) atomicAdd(&cnt[NN1 + dst1[i - E0]], 1);
        else if (i < ETOT) atomicAdd(&cnt[NN1 + NN2 + dst2[i - E0 - E1]], 1);
        return;
    }
    b -= CB;
    if (b < 128) {
        int idx = b * 256 + t; int n = idx >> 7, k = idx & 127;
        Wt0a[idx] = f2bf(k < 100 ? Wl0[k * 256 + n] : 0.f);
    } else if (b < 256) {
        int idx = (b - 128) * 256 + t; int n = idx >> 7, k = idx & 127;
        Wt0b[idx] = f2bf(k < 100 ? Wr0[k * 256 + n] : 0.f);
    } else if (b < 512) {
        int idx = (b - 256) * 256 + t; int n = idx >> 8, k = idx & 255;
        Wt1a[idx] = f2bf(Wl1[k * 256 + n]);
    } else {
        int idx = (b - 512) * 256 + t; int n = idx >> 8, k = idx & 255;
        Wt1b[idx] = f2bf(Wr1[k * 256 + n]);
    }
}

__global__ __launch_bounds__(1024) void scan1(const int* __restrict__ cnt, int n,
                                              int* __restrict__ ofs, int* __restrict__ sums) {
    __shared__ int s[1024];
    int i = blockIdx.x * 1024 + threadIdx.x;
    int v = (i < n) ? cnt[i] : 0;
    s[threadIdx.x] = v;
    __syncthreads();
    for (int off = 1; off < 1024; off <<= 1) {
        int t = (threadIdx.x >= off) ? s[threadIdx.x - off] : 0;
        __syncthreads();
        s[threadIdx.x] += t;
        __syncthreads();
    }
    if (i < n) ofs[i] = s[threadIdx.x] - v;
    if (threadIdx.x == 1023) sums[blockIdx.x] = s[1023];
}

__global__ void scan3(const int* __restrict__ sums, int n,
                      int* __restrict__ ofs, int* __restrict__ cursor) {
    __shared__ int pref_s;
    int c = (blockIdx.x * 256) >> 10;
    if (threadIdx.x < 64) {
        int v = 0;
        for (int j = threadIdx.x; j < c; j += 64) v += sums[j];
        for (int o = 32; o; o >>= 1) v += __shfl_down(v, o);
        if (threadIdx.x == 0) pref_s = v;
    }
    __syncthreads();
    int i = blockIdx.x * 256 + threadIdx.x;
    if (i < n) {
        int v = ofs[i] + pref_s;
        ofs[i] = v;
        cursor[i] = v;
    }
    if (blockIdx.x == 0 && threadIdx.x == 0) ofs[n] = ETOT;
}

__global__ void scatter_all(const int* __restrict__ src0, const int* __restrict__ dst0,
                            const int* __restrict__ src1, const int* __restrict__ dst1,
                            const int* __restrict__ src2, const int* __restrict__ dst2,
                            int* __restrict__ cursor, int* __restrict__ perm) {
    int i = blockIdx.x * 256 + threadIdx.x;
    if (i < E0) {
        int p = atomicAdd(&cursor[dst0[i]], 1);
        perm[p] = src0[i];
    } else if (i < E0 + E1) {
        int j = i - E0;
        int p = atomicAdd(&cursor[NN1 + dst1[j]], 1);
        perm[p] = src1[j];
    } else if (i < ETOT) {
        int j = i - E0 - E1;
        int p = atomicAdd(&cursor[NN1 + NN2 + dst2[j]], 1);
        perm[p] = src2[j];
    }
}

// ---------- fused layer 0: gather-mean(x fp32) + dual MFMA GEMM + ReLU -> h1 bf16 ----------
// Block: 128 dst rows x full N=256, 512 threads (8 waves).
// Gather: offsets prefetched (1 load/wave), perm prefetched (1 coalesced load/row),
// masked batches of 8 edges (dual lane groups x unroll 4), no serial remainder.
__global__ __launch_bounds__(512, 4) void fused_l0(const float* __restrict__ x,
                                                   const int* __restrict__ perm,
                                                   const int* __restrict__ ofs,
                                                   const unsigned short* __restrict__ Wt0a,
                                                   const unsigned short* __restrict__ Wt0b,
                                                   const float* __restrict__ bias,
                                                   unsigned short* __restrict__ h1) {
    __shared__ unsigned short As[128][136];
    __shared__ unsigned short Bs[256][40];
    int tid = threadIdx.x;
    int lane = tid & 63, wid = tid >> 6;
    int bm = blockIdx.x * 128;

    // ---- gather phase ----
    {
        int g = lane >> 5, l5 = lane & 31;
        bool act = l5 < 25;
        int node0 = bm + wid * 16;
        int myofs = (lane < 17) ? ofs[node0 + lane] : 0;
        for (int r = 0; r < 16; ++r) {
            int row = wid * 16 + r;
            int s0 = __shfl(myofs, r), s1 = __shfl(myofs, r + 1);
            int deg = s1 - s0;
            float inv = 1.0f / fmaxf((float)deg, 1.0f);
            int dcap = min(deg, 64);
            int pe = (lane < dcap) ? perm[s0 + lane] : 0;
            f32x4_t A0 = {0.f, 0.f, 0.f, 0.f}, A1 = A0, A2 = A0, A3 = A0;
            for (int b = 0; b < dcap; b += 8) {
                int e0 = b + g, e1 = b + 2 + g, e2 = b + 4 + g, e3 = b + 6 + g;
                int p0 = __shfl(pe, e0), p1 = __shfl(pe, e1);
                int p2 = __shfl(pe, e2), p3 = __shfl(pe, e3);
                f32x4_t v0 = {0.f, 0.f, 0.f, 0.f}, v1 = v0, v2 = v0, v3 = v0;
                if (act && e0 < dcap) v0 = *reinterpret_cast<const f32x4_t*>(x + (size_t)p0 * 100 + l5 * 4);
                if (act && e1 < dcap) v1 = *reinterpret_cast<const f32x4_t*>(x + (size_t)p1 * 100 + l5 * 4);
                if (act && e2 < dcap) v2 = *reinterpret_cast<const f32x4_t*>(x + (size_t)p2 * 100 + l5 * 4);
                if (act && e3 < dcap) v3 = *reinterpret_cast<const f32x4_t*>(x + (size_t)p3 * 100 + l5 * 4);
                A0 += v0; A1 += v1; A2 += v2; A3 += v3;
            }
            for (int e = s0 + 64; e < s1; e += 2) {   // deg>64 fallback (effectively never)
                int idx = e + g;
                if (act && idx < s1)
                    A0 += *reinterpret_cast<const f32x4_t*>(x + (size_t)perm[idx] * 100 + l5 * 4);
            }
            f32x4_t a = (A0 + A1) + (A2 + A3);
#pragma unroll
            for (int c = 0; c < 4; c++) a[c] += __shfl_xor(a[c], 32);
            if (lane < 25) {
                ushort4 o;
                o.x = f2bf(a[0] * inv); o.y = f2bf(a[1] * inv);
                o.z = f2bf(a[2] * inv); o.w = f2bf(a[3] * inv);
                *reinterpret_cast<ushort4*>(&As[row][lane * 4]) = o;
            } else if (lane < 32) {
                *reinterpret_cast<ushort4*>(&As[row][100 + (lane - 25) * 4]) = make_ushort4(0, 0, 0, 0);
            }
        }
    }

    f32x4_t acc[4][4];
#pragma unroll
    for (int i = 0; i < 4; i++)
#pragma unroll
        for (int j = 0; j < 4; j++)
#pragma unroll
            for (int r = 0; r < 4; r++) acc[i][j][r] = 0.f;

    int r0 = lane & 15, kg = lane >> 4;
    int wm = (wid >> 2) * 64, wn = (wid & 3) * 64;

    for (int pass = 0; pass < 2; ++pass) {
        const unsigned short* W = pass ? Wt0b : Wt0a;
        if (pass) {
            __syncthreads();   // all pass-0 MFMA done reading As
            // re-stage As <- x dst rows (fp32 -> bf16), 4 threads/row
            int rown = tid >> 2, q = tid & 3;
            for (int c4 = q; c4 < 25; c4 += 4) {
                f32x4_t v = *reinterpret_cast<const f32x4_t*>(x + (size_t)(bm + rown) * 100 + c4 * 4);
                ushort4 o;
                o.x = f2bf(v[0]); o.y = f2bf(v[1]); o.z = f2bf(v[2]); o.w = f2bf(v[3]);
                *reinterpret_cast<ushort4*>(&As[rown][c4 * 4]) = o;
            }
            if (q == 3) {
#pragma unroll
                for (int c4 = 25; c4 < 32; ++c4)
                    *reinterpret_cast<ushort4*>(&As[rown][c4 * 4]) = make_ushort4(0, 0, 0, 0);
            }
        }
        for (int ks = 0; ks < 4; ++ks) {
            __syncthreads();
            for (int c = tid; c < 1024; c += 512) {
                int n = c >> 2, k8 = (c & 3) << 3;
                *reinterpret_cast<int4*>(&Bs[n][k8]) =
                    *reinterpret_cast<const int4*>(&W[(size_t)n * 128 + ks * 32 + k8]);
            }
            __syncthreads();
            bf16x8_t af[4], bfv[4];
#pragma unroll
            for (int mi = 0; mi < 4; mi++)
                af[mi] = *reinterpret_cast<const bf16x8_t*>(&As[wm + mi * 16 + r0][ks * 32 + kg * 8]);
#pragma unroll
            for (int ni = 0; ni < 4; ni++)
                bfv[ni] = *reinterpret_cast<const bf16x8_t*>(&Bs[wn + ni * 16 + r0][kg * 8]);
#pragma unroll
            for (int mi = 0; mi < 4; mi++)
#pragma unroll
                for (int ni = 0; ni < 4; ni++)
                    acc[mi][ni] = __builtin_amdgcn_mfma_f32_16x16x32_bf16(af[mi], bfv[ni], acc[mi][ni], 0, 0, 0);
        }
    }

    int cc = lane & 15, rr = (lane >> 4) * 4;
#pragma unroll
    for (int mi = 0; mi < 4; mi++) {
#pragma unroll
        for (int ni = 0; ni < 4; ni++) {
            int col = wn + ni * 16 + cc;
            float b = bias[col];
#pragma unroll
            for (int j = 0; j < 4; j++) {
                int row = bm + wm + mi * 16 + rr + j;
                float v = fmaxf(acc[mi][ni][j] + b, 0.f);
                h1[(size_t)row * 256 + col] = f2bf(v);
            }
        }
    }
}

// ---------- fused layer 1: gather-mean(h1 bf16) + dual MFMA GEMM + ReLU -> h2 fp32 ----------
__global__ __launch_bounds__(512, 4) void fused_l1(const unsigned short* __restrict__ h1,
                                                   const int* __restrict__ perm,
                                                   const int* __restrict__ ofs,
                                                   const unsigned short* __restrict__ Wt1a,
                                                   const unsigned short* __restrict__ Wt1b,
                                                   const float* __restrict__ bias,
                                                   float* __restrict__ h2) {
    __shared__ unsigned short As[64][264];
    __shared__ unsigned short Bs[128][40];
    int tid = threadIdx.x;
    int lane = tid & 63, wid = tid >> 6;
    int bm = blockIdx.y * 64, bn = blockIdx.x * 128;

    {
        int node0 = bm + wid * 8;
        int myofs = (lane < 9) ? ofs[node0 + lane] : 0;
        for (int r = 0; r < 8; ++r) {
            int row = wid * 8 + r;
            int s0 = __shfl(myofs, r), s1 = __shfl(myofs, r + 1);
            int deg = s1 - s0;
            float inv = 1.0f / fmaxf((float)deg, 1.0f);
            int dcap = min(deg, 64);
            int pe = (lane < dcap) ? perm[s0 + lane] : 0;
            float ac[4][4] = {};
            for (int b = 0; b < dcap; b += 4) {
#pragma unroll
                for (int u = 0; u < 4; u++) {
                    int pu = __shfl(pe, b + u);
                    ushort4 v = make_ushort4(0, 0, 0, 0);
                    if (b + u < dcap)
                        v = *reinterpret_cast<const ushort4*>(h1 + (size_t)pu * 256 + lane * 4);
                    ac[u][0] += bf2f(v.x); ac[u][1] += bf2f(v.y);
                    ac[u][2] += bf2f(v.z); ac[u][3] += bf2f(v.w);
                }
            }
            for (int e = s0 + 64; e < s1; e++) {   // deg>64 fallback
                ushort4 v = *reinterpret_cast<const ushort4*>(h1 + (size_t)perm[e] * 256 + lane * 4);
                ac[0][0] += bf2f(v.x); ac[0][1] += bf2f(v.y);
                ac[0][2] += bf2f(v.z); ac[0][3] += bf2f(v.w);
            }
            ushort4 o;
            o.x = f2bf((ac[0][0] + ac[1][0] + ac[2][0] + ac[3][0]) * inv);
            o.y = f2bf((ac[0][1] + ac[1][1] + ac[2][1] + ac[3][1]) * inv);
            o.z = f2bf((ac[0][2] + ac[1][2] + ac[2][2] + ac[3][2]) * inv);
            o.w = f2bf((ac[0][3] + ac[1][3] + ac[2][3] + ac[3][3]) * inv);
            *reinterpret_cast<ushort4*>(&As[row][lane * 4]) = o;
        }
    }

    f32x4_t acc[2][2];
#pragma unroll
    for (int i = 0; i < 2; i++)
#pragma unroll
        for (int j = 0; j < 2; j++)
#pragma unroll
            for (int r = 0; r < 4; r++) acc[i][j][r] = 0.f;

    int r0 = lane & 15, kg = lane >> 4;
    int wm = (wid >> 2) * 32, wn = (wid & 3) * 32;

    for (int pass = 0; pass < 2; ++pass) {
        const unsigned short* W = pass ? Wt1b : Wt1a;
        if (pass) {
            __syncthreads();
            for (int c = tid; c < 2048; c += 512) {
                int row = c >> 5, k8 = (c & 31) << 3;
                *reinterpret_cast<int4*>(&As[row][k8]) =
                    *reinterpret_cast<const int4*>(&h1[(size_t)(bm + row) * 256 + k8]);
            }
        }
        for (int ks = 0; ks < 8; ++ks) {
            __syncthreads();
            {
                int c = tid;
                int n = c >> 2, k8 = (c & 3) << 3;
                *reinterpret_cast<int4*>(&Bs[n][k8]) =
                    *reinterpret_cast<const int4*>(&W[(size_t)(bn + n) * 256 + ks * 32 + k8]);
            }
            __syncthreads();
            bf16x8_t af[2], bfv[2];
#pragma unroll
            for (int mi = 0; mi < 2; mi++)
                af[mi] = *reinterpret_cast<const bf16x8_t*>(&As[wm + mi * 16 + r0][ks * 32 + kg * 8]);
#pragma unroll
            for (int ni = 0; ni < 2; ni++)
                bfv[ni] = *reinterpret_cast<const bf16x8_t*>(&Bs[wn + ni * 16 + r0][kg * 8]);
#pragma unroll
            for (int mi = 0; mi < 2; mi++)
#pragma unroll
                for (int ni = 0; ni < 2; ni++)
                    acc[mi][ni] = __builtin_amdgcn_mfma_f32_16x16x32_bf16(af[mi], bfv[ni], acc[mi][ni], 0, 0, 0);
        }
    }

    int cc = lane & 15, rr = (lane >> 4) * 4;
#pragma unroll
    for (int mi = 0; mi < 2; mi++) {
#pragma unroll
        for (int ni = 0; ni < 2; ni++) {
            int col = bn + wn + ni * 16 + cc;
            float b = bias[col];
#pragma unroll
            for (int j = 0; j < 4; j++) {
                int row = bm + wm + mi * 16 + rr + j;
                h2[(size_t)row * 256 + col] = fmaxf(acc[mi][ni][j] + b, 0.f);
            }
        }
    }
}

// ---------- layer 2 all-in-one: gather-mean(h2) in LDS + fp32 dual GEMM + log_softmax ----------
// Grid (1, 16); block = 64 rows x full N=47, 256 threads (4 waves).
__global__ __launch_bounds__(256) void gemm2_all(const float* __restrict__ h2,
                                                 const int* __restrict__ perm,
                                                 const int* __restrict__ ofs,
                                                 const float* __restrict__ W1,   // Wl2 [256][47]
                                                 const float* __restrict__ W2,   // Wr2 [256][47]
                                                 const float* __restrict__ bias,
                                                 float* __restrict__ out,
                                                 int M, int N) {
    __shared__ float Agg[64][260];   // fp32 aggregated rows (stride 260: 16B-aligned float4 slots)
    __shared__ float As[16][65];
    __shared__ float Bs[16][64];
    int tid = threadIdx.x;
    int lane = tid & 63, wid = tid >> 6;
    int bm = blockIdx.y * 64;

    // ---- gather phase: wave wid handles rows [wid*16, wid*16+16) ----
    {
        int node0 = bm + wid * 16;
        int myofs = (lane < 17) ? ofs[node0 + lane] : 0;
        for (int r = 0; r < 16; ++r) {
            int row = wid * 16 + r;
            int s0 = __shfl(myofs, r), s1 = __shfl(myofs, r + 1);
            int deg = s1 - s0;
            float inv = 1.0f / fmaxf((float)deg, 1.0f);
            int dcap = min(deg, 64);
            int pe = (lane < dcap) ? perm[s0 + lane] : 0;
            f32x4_t B0 = {0.f, 0.f, 0.f, 0.f}, B1 = B0, B2 = B0, B3 = B0;
            for (int b = 0; b < dcap; b += 4) {
                int p0 = __shfl(pe, b), p1 = __shfl(pe, b + 1);
                int p2 = __shfl(pe, b + 2), p3 = __shfl(pe, b + 3);
                f32x4_t v0 = {0.f, 0.f, 0.f, 0.f}, v1 = v0, v2 = v0, v3 = v0;
                if (b < dcap)     v0 = *reinterpret_cast<const f32x4_t*>(h2 + (size_t)p0 * 256 + lane * 4);
                if (b + 1 < dcap) v1 = *reinterpret_cast<const f32x4_t*>(h2 + (size_t)p1 * 256 + lane * 4);
                if (b + 2 < dcap) v2 = *reinterpret_cast<const f32x4_t*>(h2 + (size_t)p2 * 256 + lane * 4);
                if (b + 3 < dcap) v3 = *reinterpret_cast<const f32x4_t*>(h2 + (size_t)p3 * 256 + lane * 4);
                B0 += v0; B1 += v1; B2 += v2; B3 += v3;
            }
            for (int e = s0 + 64; e < s1; e++)   // deg>64 fallback
                B0 += *reinterpret_cast<const f32x4_t*>(h2 + (size_t)perm[e] * 256 + lane * 4);
            f32x4_t a = (B0 + B1) + (B2 + B3);
#pragma unroll
            for (int c = 0; c < 4; c++) Agg[row][lane * 4 + c] = a[c] * inv;
        }
    }
    __syncthreads();

    int tx = tid & 15, ty = tid >> 4;
    float acc[4][4] = {};
    for (int pass = 0; pass < 2; ++pass) {
        const float* W = pass ? W2 : W1;
        for (int k0 = 0; k0 < 256; k0 += 16) {
            __syncthreads();
#pragma unroll
            for (int i = 0; i < 4; i++) {
                int L = i * 256 + tid;
                int m = L >> 4, k = L & 15;
                As[k][m] = pass ? h2[(size_t)(bm + m) * 256 + k0 + k] : Agg[m][k0 + k];
            }
#pragma unroll
            for (int i = 0; i < 4; i++) {
                int L = i * 256 + tid;
                int n = L & 63, k = L >> 6;
                float v = 0.f;
                if (n < N) v = W[(size_t)(k0 + k) * N + n];
                Bs[k][n] = v;
            }
            __syncthreads();
#pragma unroll
            for (int k = 0; k < 16; k++) {
                float a[4], b[4];
#pragma unroll
                for (int i = 0; i < 4; i++) a[i] = As[k][ty * 4 + i];
#pragma unroll
                for (int j = 0; j < 4; j++) b[j] = Bs[k][tx * 4 + j];
#pragma unroll
                for (int i = 0; i < 4; i++)
#pragma unroll
                    for (int j = 0; j < 4; j++) acc[i][j] += a[i] * b[j];
            }
        }
    }
    // fused bias + log_softmax per row
#pragma unroll
    for (int i = 0; i < 4; i++) {
        int gm = bm + ty * 4 + i;
        float vals[4];
        float vmax = -1e30f;
#pragma unroll
        for (int j = 0; j < 4; j++) {
            int gn = tx * 4 + j;
            vals[j] = (gn < N) ? acc[i][j] + bias[gn] : -1e30f;
            vmax = fmaxf(vmax, vals[j]);
        }
#pragma unroll
        for (int o = 1; o < 16; o <<= 1) vmax = fmaxf(vmax, __shfl_xor(vmax, o));
        float se = 0.f;
#pragma unroll
        for (int j = 0; j < 4; j++) {
            int gn = tx * 4 + j;
            if (gn < N) se += expf(vals[j] - vmax);
        }
#pragma unroll
        for (int o = 1; o < 16; o <<= 1) se += __shfl_xor(se, o);
        float ls = logf(se);
#pragma unroll
        for (int j = 0; j < 4; j++) {
            int gn = tx * 4 + j;
            if (gn < N && gm < M) out[(size_t)gm * N + gn] = vals[j] - vmax - ls;
        }
    }
}

extern "C" void kernel_launch(void* const* d_in, const int* in_sizes, int n_in,
                              void* d_out, int out_size, void* d_ws, size_t ws_size,
                              hipStream_t stream) {
    const float* x   = (const float*)d_in[0];
    const int* src0  = (const int*)d_in[1];
    const int* dst0  = (const int*)d_in[2];
    const int* src1  = (const int*)d_in[3];
    const int* dst1  = (const int*)d_in[4];
    const int* src2  = (const int*)d_in[5];
    const int* dst2  = (const int*)d_in[6];
    const float* Wl0 = (const float*)d_in[7];
    const float* bl0 = (const float*)d_in[8];
    const float* Wr0 = (const float*)d_in[9];
    const float* Wl1 = (const float*)d_in[10];
    const float* bl1 = (const float*)d_in[11];
    const float* Wr1 = (const float*)d_in[12];
    const float* Wl2 = (const float*)d_in[13];
    const float* bl2 = (const float*)d_in[14];
    const float* Wr2 = (const float*)d_in[15];
    float* out = (float*)d_out;

    // ---- workspace layout ----
    char* p = (char*)d_ws;
    auto alloc = [&](size_t bytes) { char* r = p; p += (bytes + 255) & ~(size_t)255; return r; };
    unsigned short* h1   = (unsigned short*)alloc((size_t)NN1 * 256 * 2);
    float* h2    = (float*)alloc((size_t)NN2 * 256 * 4);
    unsigned short* Wt0a = (unsigned short*)alloc(256 * 128 * 2);
    unsigned short* Wt0b = (unsigned short*)alloc(256 * 128 * 2);
    unsigned short* Wt1a = (unsigned short*)alloc(256 * 256 * 2);
    unsigned short* Wt1b = (unsigned short*)alloc(256 * 256 * 2);
    int* cnt    = (int*)alloc((size_t)NTOT * 4);
    int* ofs    = (int*)alloc((size_t)(NTOT + 1) * 4);
    int* cursor = (int*)alloc((size_t)(NTOT + 1) * 4);
    int* sums   = (int*)alloc(128 * 4);
    int* perm   = (int*)alloc((size_t)ETOT * 4);

    // ---- CSR build + weight prep ----
    hipMemsetAsync(cnt, 0, (size_t)NTOT * 4, stream);
    count_prep<<<CB + 768, 256, 0, stream>>>(dst0, dst1, dst2, cnt,
                                             Wl0, Wr0, Wt0a, Wt0b, Wl1, Wr1, Wt1a, Wt1b);
    int nb = cdiv(NTOT, 1024);   // 73
    scan1<<<nb, 1024, 0, stream>>>(cnt, NTOT, ofs, sums);
    scan3<<<cdiv(NTOT, 256), 256, 0, stream>>>(sums, NTOT, ofs, cursor);
    scatter_all<<<cdiv(ETOT, 256), 256, 0, stream>>>(src0, dst0, src1, dst1, src2, dst2, cursor, perm);

    // ---- layer 0 ----
    fused_l0<<<NN1 / 128, 512, 0, stream>>>(x, perm, ofs, Wt0a, Wt0b, bl0, h1);

    // ---- layer 1 ----
    {
        dim3 grid(2, NN2 / 64);
        fused_l1<<<grid, 512, 0, stream>>>(h1, perm, ofs + NN1, Wt1a, Wt1b, bl1, h2);
    }

    // ---- layer 2 (gather + dual GEMM + log_softmax, one kernel) ----
    {
        dim3 grid(1, NN3 / 64);
        gemm2_all<<<grid, 256, 0, stream>>>(h2, perm, ofs + NN1 + NN2, Wl2, Wr2, bl2, out, NN3, 47);
    }
}